// Round 1
// baseline (1048.091 us; speedup 1.0000x reference)
//
#include <hip/hip_runtime.h>
#include <hip/hip_bf16.h>
#include <math.h>

// Output: concat([hte_feat, desc_feat], -1) -> (B, 2*C*H) fp32.
// Sizes derived at launch: L=in_sizes[2], C*H=in_sizes[3], B=out_size/(2*C*H),
// T=in_sizes[1]/B, H=in_sizes[0]/((L+1)*B*T), C=(C*H)/H.

#define CMAX 8
#define KMAX 4

// ---------------- Kernel A: per-batch scan ----------------
__global__ void mha_scan(const int* __restrict__ ids, const int* __restrict__ hte_id_p,
                         const int* __restrict__ dtok, int nD, int T,
                         int* __restrict__ pos_out, int* __restrict__ nd_out,
                         int* __restrict__ dlist) {
    int b = blockIdx.x;
    __shared__ int s_pos, s_cnt;
    if (threadIdx.x == 0) { s_pos = 0x7fffffff; s_cnt = 0; }
    __syncthreads();
    const int hte = hte_id_p[0];
    const int* row = ids + (size_t)b * T;
    for (int t = threadIdx.x; t < T; t += blockDim.x) {
        int id = row[t];
        if (id == hte) atomicMin(&s_pos, t);
        bool isd = false;
        for (int j = 0; j < nD; ++j) isd |= (id == dtok[j]);
        if (isd) {
            int slot = atomicAdd(&s_cnt, 1);
            dlist[(size_t)b * T + slot] = t;
        }
    }
    __syncthreads();
    if (threadIdx.x == 0) {
        pos_out[b] = (s_pos == 0x7fffffff) ? (T - 1) : s_pos;
        if (s_cnt == 0) { dlist[(size_t)b * T] = 0; nd_out[b] = 1; }
        else nd_out[b] = s_cnt;
    }
}

// ---------------- Kernel B: masked pool per (part, layer, batch) ----------------
// grid = 2*L*B blocks, 256 threads. Dynamic LDS:
//   lds_W  [C*H]  | lds_sc [T*C] (scores -> attn) | lds_ms [2*C] | lds_pos [T] ints
__global__ void mha_pool(const float* __restrict__ hs, const float* __restrict__ logits,
                         const float* __restrict__ W, const int* __restrict__ win_p,
                         const int* __restrict__ pos_in, const int* __restrict__ nd_in,
                         const int* __restrict__ dlist,
                         int L, int B, int T, int H, int C,
                         float* __restrict__ partial) {
    extern __shared__ float smem[];
    float* lds_W   = smem;                          // C*H
    float* lds_sc  = lds_W + (size_t)C * H;         // T*C
    float* lds_ms  = lds_sc + (size_t)T * C;        // 2*C
    int*   lds_pos = (int*)(lds_ms + 2 * C);        // T

    const int bx   = blockIdx.x;
    const int part = bx / (L * B);                  // 0 = hte, 1 = desc
    const int rem  = bx % (L * B);
    const int l    = rem / B;
    const int b    = rem % B;
    const int tid  = threadIdx.x;
    const int lane = tid & 63;
    const int wave = tid >> 6;
    const int nwaves = blockDim.x >> 6;

    // Load W into LDS
    for (int i = tid; i < C * H; i += blockDim.x) lds_W[i] = W[i];

    // Positions
    int npos, p0 = 0;
    if (part == 0) {
        npos = win_p[0] + 1;
        p0 = pos_in[b];
        for (int p = tid; p < npos; p += blockDim.x) {
            int t = p0 + p;
            lds_pos[p] = (t < T) ? t : (T - 1);     // clipped; validity handled via score
        }
    } else {
        npos = nd_in[b];
        for (int p = tid; p < npos; p += blockDim.x)
            lds_pos[p] = dlist[(size_t)b * T + p];
    }
    __syncthreads();

    const float* base = hs + ((size_t)(l + 1) * B + b) * (size_t)T * H;

    // Pass 1: scores[p][c] = dot(h_t, W_c); invalid -> -1e30
    for (int p = wave; p < npos; p += nwaves) {
        int t = lds_pos[p];
        bool valid = (part != 0) || (p0 + p < T);
        const float* v = base + (size_t)t * H;
        float s[CMAX];
        #pragma unroll
        for (int c = 0; c < CMAX; ++c) s[c] = 0.f;
        for (int h = lane; h < H; h += 64) {
            float x = v[h];
            for (int c = 0; c < C; ++c) s[c] += x * lds_W[c * H + h];
        }
        for (int c = 0; c < C; ++c) {
            float r = s[c];
            for (int off = 32; off > 0; off >>= 1) r += __shfl_down(r, off);
            if (lane == 0) lds_sc[p * C + c] = valid ? r : -1e30f;
        }
    }
    __syncthreads();

    // Softmax over positions, per head c (one wave per c)
    for (int c = wave; c < C; c += nwaves) {
        float m = -1e30f;
        for (int p = lane; p < npos; p += 64) m = fmaxf(m, lds_sc[p * C + c]);
        for (int off = 32; off > 0; off >>= 1) m = fmaxf(m, __shfl_xor(m, off));
        float sum = 0.f;
        for (int p = lane; p < npos; p += 64) sum += expf(lds_sc[p * C + c] - m);
        for (int off = 32; off > 0; off >>= 1) sum += __shfl_xor(sum, off);
        if (lane == 0) { lds_ms[c] = m; lds_ms[C + c] = sum; }
    }
    __syncthreads();
    for (int i = tid; i < npos * C; i += blockDim.x) {
        int c = i % C;
        lds_sc[i] = expf(lds_sc[i] - lds_ms[c]) / lds_ms[C + c];
    }
    __syncthreads();

    // Pass 2: pooled[c][h] = sum_p attn[p][c] * h_t[h]
    const int K = (H + blockDim.x - 1) / blockDim.x;
    float acc[CMAX][KMAX];
    #pragma unroll
    for (int c = 0; c < CMAX; ++c)
        #pragma unroll
        for (int k = 0; k < KMAX; ++k) acc[c][k] = 0.f;

    for (int p = 0; p < npos; ++p) {
        int t = lds_pos[p];
        const float* v = base + (size_t)t * H;
        float a[CMAX];
        for (int c = 0; c < C; ++c) a[c] = lds_sc[p * C + c];
        for (int k = 0; k < K; ++k) {
            int h = tid + k * blockDim.x;
            if (h < H) {
                float x = v[h];
                for (int c = 0; c < C; ++c) acc[c][k] += a[c] * x;
            }
        }
    }

    // Layer weight wl[l] = softmax(logits)[l] (computed redundantly; L is tiny)
    float mL = -1e30f;
    for (int i = 0; i < L; ++i) mL = fmaxf(mL, logits[i]);
    float sL = 0.f;
    for (int i = 0; i < L; ++i) sL += expf(logits[i] - mL);
    float wl = expf(logits[l] - mL) / sL;

    float* outp = partial + ((size_t)(part * L + l) * B + b) * ((size_t)C * H);
    for (int k = 0; k < K; ++k) {
        int h = tid + k * blockDim.x;
        if (h < H)
            for (int c = 0; c < C; ++c) outp[c * H + h] = wl * acc[c][k];
    }
}

// ---------------- Kernel C: sum over layers, write concat output ----------------
__global__ void mha_combine(const float* __restrict__ partial, float* __restrict__ out,
                            int L, int B, int CH, int n) {
    int idx = blockIdx.x * blockDim.x + threadIdx.x;
    if (idx >= n) return;
    int b    = idx / (2 * CH);
    int r    = idx % (2 * CH);
    int part = r / CH;
    int ch   = r % CH;
    float s = 0.f;
    for (int l = 0; l < L; ++l)
        s += partial[((size_t)(part * L + l) * B + b) * (size_t)CH + ch];
    out[idx] = s;
}

extern "C" void kernel_launch(void* const* d_in, const int* in_sizes, int n_in,
                              void* d_out, int out_size, void* d_ws, size_t ws_size,
                              hipStream_t stream) {
    const float* hs     = (const float*)d_in[0];
    const int*   ids    = (const int*)d_in[1];
    const float* logits = (const float*)d_in[2];
    const float* W      = (const float*)d_in[3];
    const int*   hte_id = (const int*)d_in[4];
    const int*   dtok   = (const int*)d_in[5];
    const int*   win    = (const int*)d_in[6];

    const int L  = in_sizes[2];                 // 8
    const int CH = in_sizes[3];                 // C*H = 3072
    const int BT = in_sizes[1];                 // B*T
    const int B  = out_size / (2 * CH);         // 16
    const int T  = BT / B;                      // 2048
    const long long total = (long long)in_sizes[0];
    const int H  = (int)(total / ((long long)(L + 1) * BT));  // 768
    const int C  = CH / H;                      // 4
    const int nD = in_sizes[5];                 // 3

    // Workspace layout
    char* ws = (char*)d_ws;
    int* pos   = (int*)ws;
    int* nd    = pos + B;
    int* dlist = nd + B;
    uintptr_t poff = (uintptr_t)(dlist + (size_t)B * T);
    poff = (poff + 15) & ~(uintptr_t)15;
    float* partial = (float*)poff;

    mha_scan<<<B, 256, 0, stream>>>(ids, hte_id, dtok, nD, T, pos, nd, dlist);

    size_t smem = ((size_t)C * H + (size_t)T * C + 2 * C) * sizeof(float)
                + (size_t)T * sizeof(int);      // ~52 KB for this shape
    mha_pool<<<2 * L * B, 256, smem, stream>>>(hs, logits, W, win, pos, nd, dlist,
                                               L, B, T, H, C, partial);

    mha_combine<<<(out_size + 255) / 256, 256, 0, stream>>>(partial, (float*)d_out,
                                                            L, B, CH, out_size);
}

// Round 2
// 979.312 us; speedup vs baseline: 1.0702x; 1.0702x over previous
//
#include <hip/hip_runtime.h>
#include <hip/hip_bf16.h>
#include <math.h>

// Output: concat([hte_feat, desc_feat], -1) -> (B, 2*C*H) fp32.
// Fully fused: one zero-kernel + one pool kernel.
// Each block handles one (part, layer, batch): re-scans its id row (8 KB),
// computes masked-softmax attention pool over the ~5..17 live positions,
// scales by softmax(layer_logits)[l], and atomicAdds into d_out.

#define CMAX 8
#define KMAX 4

__global__ void mha_zero(float* __restrict__ out, int n) {
    int i = blockIdx.x * blockDim.x + threadIdx.x;
    if (i < n) out[i] = 0.f;
}

// ---------------- Fused kernel (compile-time C, K) ----------------
// grid = 2*L*B blocks, 256 threads. Dynamic LDS:
//   lds_W [C*H] | lds_sc [T*C] | lds_ms [2*C] | lds_pos [T] ints
template <int C, int K>
__global__ void mha_fused(const float* __restrict__ hs, const float* __restrict__ logits,
                          const float* __restrict__ W, const int* __restrict__ ids,
                          const int* __restrict__ hte_p, const int* __restrict__ dtok,
                          int nD, const int* __restrict__ win_p,
                          int L, int B, int T, int H,
                          float* __restrict__ out) {
    extern __shared__ float smem[];
    float* lds_W   = smem;                       // C*H
    float* lds_sc  = lds_W + (size_t)C * H;      // T*C
    float* lds_ms  = lds_sc + (size_t)T * C;     // 2*C
    int*   lds_pos = (int*)(lds_ms + 2 * C);     // T
    __shared__ int s_pos, s_cnt;

    const int bx   = blockIdx.x;
    const int part = bx / (L * B);               // 0 = hte, 1 = desc
    const int rem  = bx % (L * B);
    const int l    = rem / B;
    const int b    = rem % B;
    const int tid  = threadIdx.x;
    const int lane = tid & 63;
    const int wave = tid >> 6;
    const int nwaves = blockDim.x >> 6;

    if (tid == 0) { s_pos = 0x7fffffff; s_cnt = 0; }
    // Load W into LDS (overlaps with scan)
    for (int i = tid; i < C * H; i += blockDim.x) lds_W[i] = W[i];
    __syncthreads();

    // ---- In-block scan of this batch row ----
    const int hte = hte_p[0];
    const int* row = ids + (size_t)b * T;
    for (int t = tid; t < T; t += blockDim.x) {
        int id = row[t];
        if (id == hte) atomicMin(&s_pos, t);
        if (part == 1) {
            bool isd = false;
            for (int j = 0; j < nD; ++j) isd |= (id == dtok[j]);
            if (isd) {
                int slot = atomicAdd(&s_cnt, 1);
                lds_pos[slot] = t;
            }
        }
    }
    __syncthreads();

    int npos, p0 = 0;
    if (part == 0) {
        npos = win_p[0] + 1;
        p0 = (s_pos == 0x7fffffff) ? (T - 1) : s_pos;
        for (int p = tid; p < npos; p += blockDim.x) {
            int t = p0 + p;
            lds_pos[p] = (t < T) ? t : (T - 1);  // validity handled via score
        }
    } else {
        npos = s_cnt;
        if (npos == 0) { if (tid == 0) lds_pos[0] = 0; npos = 1; }
    }
    __syncthreads();

    const float* base = hs + ((size_t)(l + 1) * B + b) * (size_t)T * H;

    // ---- Pass 1: scores[p][c] = dot(h_t, W_c); invalid -> -1e30 (float4 loads) ----
    const int H4 = H >> 2;
    const float4* lds_W4 = (const float4*)lds_W;
    for (int p = wave; p < npos; p += nwaves) {
        int t = lds_pos[p];
        bool valid = (part != 0) || (p0 + p < T);
        const float4* v = (const float4*)(base + (size_t)t * H);
        float s[C];
        #pragma unroll
        for (int c = 0; c < C; ++c) s[c] = 0.f;
        for (int i = lane; i < H4; i += 64) {
            float4 x = v[i];
            #pragma unroll
            for (int c = 0; c < C; ++c) {
                float4 w = lds_W4[c * H4 + i];
                s[c] += x.x * w.x + x.y * w.y + x.z * w.z + x.w * w.w;
            }
        }
        #pragma unroll
        for (int c = 0; c < C; ++c) {
            float r = s[c];
            for (int off = 32; off > 0; off >>= 1) r += __shfl_xor(r, off);
            if (lane == 0) lds_sc[p * C + c] = valid ? r : -1e30f;
        }
    }
    __syncthreads();

    // ---- Softmax over positions, per head c ----
    for (int c = wave; c < C; c += nwaves) {
        float m = -1e30f;
        for (int p = lane; p < npos; p += 64) m = fmaxf(m, lds_sc[p * C + c]);
        for (int off = 32; off > 0; off >>= 1) m = fmaxf(m, __shfl_xor(m, off));
        float sum = 0.f;
        for (int p = lane; p < npos; p += 64) sum += expf(lds_sc[p * C + c] - m);
        for (int off = 32; off > 0; off >>= 1) sum += __shfl_xor(sum, off);
        if (lane == 0) { lds_ms[c] = m; lds_ms[C + c] = sum; }
    }
    __syncthreads();
    for (int i = tid; i < npos * C; i += blockDim.x) {
        int c = i % C;
        lds_sc[i] = expf(lds_sc[i] - lds_ms[c]) / lds_ms[C + c];
    }
    __syncthreads();

    // ---- Pass 2: pooled[c][h] = sum_p attn[p][c] * h_t[h] (registers only) ----
    float acc[C][K];
    #pragma unroll
    for (int c = 0; c < C; ++c)
        #pragma unroll
        for (int k = 0; k < K; ++k) acc[c][k] = 0.f;

    for (int p = 0; p < npos; ++p) {
        int t = lds_pos[p];
        const float* v = base + (size_t)t * H;
        float a[C];
        #pragma unroll
        for (int c = 0; c < C; ++c) a[c] = lds_sc[p * C + c];
        #pragma unroll
        for (int k = 0; k < K; ++k) {
            int h = tid + k * blockDim.x;
            if (h < H) {
                float x = v[h];
                #pragma unroll
                for (int c = 0; c < C; ++c) acc[c][k] += a[c] * x;
            }
        }
    }

    // ---- Layer weight wl[l] = softmax(logits)[l] ----
    float mL = -1e30f;
    for (int i = 0; i < L; ++i) mL = fmaxf(mL, logits[i]);
    float sL = 0.f;
    for (int i = 0; i < L; ++i) sL += expf(logits[i] - mL);
    float wl = expf(logits[l] - mL) / sL;

    // ---- Accumulate into d_out: out[b][part*C*H + c*H + h] += wl*acc ----
    float* outp = out + (size_t)b * (2 * C * H) + (size_t)part * C * H;
    #pragma unroll
    for (int k = 0; k < K; ++k) {
        int h = tid + k * blockDim.x;
        if (h < H)
            #pragma unroll
            for (int c = 0; c < C; ++c)
                atomicAdd(&outp[c * H + h], wl * acc[c][k]);
    }
}

// ---------------- Generic fallback (runtime C, K) ----------------
__global__ void mha_fused_gen(const float* __restrict__ hs, const float* __restrict__ logits,
                              const float* __restrict__ W, const int* __restrict__ ids,
                              const int* __restrict__ hte_p, const int* __restrict__ dtok,
                              int nD, const int* __restrict__ win_p,
                              int L, int B, int T, int H, int C,
                              float* __restrict__ out) {
    extern __shared__ float smem[];
    float* lds_W   = smem;
    float* lds_sc  = lds_W + (size_t)C * H;
    float* lds_ms  = lds_sc + (size_t)T * C;
    int*   lds_pos = (int*)(lds_ms + 2 * C);
    __shared__ int s_pos, s_cnt;

    const int bx   = blockIdx.x;
    const int part = bx / (L * B);
    const int rem  = bx % (L * B);
    const int l    = rem / B;
    const int b    = rem % B;
    const int tid  = threadIdx.x;
    const int lane = tid & 63;
    const int wave = tid >> 6;
    const int nwaves = blockDim.x >> 6;

    if (tid == 0) { s_pos = 0x7fffffff; s_cnt = 0; }
    for (int i = tid; i < C * H; i += blockDim.x) lds_W[i] = W[i];
    __syncthreads();

    const int hte = hte_p[0];
    const int* row = ids + (size_t)b * T;
    for (int t = tid; t < T; t += blockDim.x) {
        int id = row[t];
        if (id == hte) atomicMin(&s_pos, t);
        if (part == 1) {
            bool isd = false;
            for (int j = 0; j < nD; ++j) isd |= (id == dtok[j]);
            if (isd) lds_pos[atomicAdd(&s_cnt, 1)] = t;
        }
    }
    __syncthreads();

    int npos, p0 = 0;
    if (part == 0) {
        npos = win_p[0] + 1;
        p0 = (s_pos == 0x7fffffff) ? (T - 1) : s_pos;
        for (int p = tid; p < npos; p += blockDim.x) {
            int t = p0 + p;
            lds_pos[p] = (t < T) ? t : (T - 1);
        }
    } else {
        npos = s_cnt;
        if (npos == 0) { if (tid == 0) lds_pos[0] = 0; npos = 1; }
    }
    __syncthreads();

    const float* base = hs + ((size_t)(l + 1) * B + b) * (size_t)T * H;

    for (int pc = wave * C; pc < npos * C; pc += nwaves * C) {
        int p = pc / C;
        int t = lds_pos[p];
        bool valid = (part != 0) || (p0 + p < T);
        const float* v = base + (size_t)t * H;
        for (int c = 0; c < C; ++c) {
            float s = 0.f;
            for (int h = lane; h < H; h += 64) s += v[h] * lds_W[c * H + h];
            for (int off = 32; off > 0; off >>= 1) s += __shfl_xor(s, off);
            if (lane == 0) lds_sc[p * C + c] = valid ? s : -1e30f;
        }
    }
    __syncthreads();

    for (int c = wave; c < C; c += nwaves) {
        float m = -1e30f;
        for (int p = lane; p < npos; p += 64) m = fmaxf(m, lds_sc[p * C + c]);
        for (int off = 32; off > 0; off >>= 1) m = fmaxf(m, __shfl_xor(m, off));
        float sum = 0.f;
        for (int p = lane; p < npos; p += 64) sum += expf(lds_sc[p * C + c] - m);
        for (int off = 32; off > 0; off >>= 1) sum += __shfl_xor(sum, off);
        if (lane == 0) { lds_ms[c] = m; lds_ms[C + c] = sum; }
    }
    __syncthreads();
    for (int i = tid; i < npos * C; i += blockDim.x) {
        int c = i % C;
        lds_sc[i] = expf(lds_sc[i] - lds_ms[c]) / lds_ms[C + c];
    }
    __syncthreads();

    float mL = -1e30f;
    for (int i = 0; i < L; ++i) mL = fmaxf(mL, logits[i]);
    float sL = 0.f;
    for (int i = 0; i < L; ++i) sL += expf(logits[i] - mL);
    float wl = expf(logits[l] - mL) / sL;

    float* outp = out + (size_t)b * (2 * C * H) + (size_t)part * C * H;
    for (int h = tid; h < H; h += blockDim.x) {
        for (int c = 0; c < C; ++c) {
            float acc = 0.f;
            for (int p = 0; p < npos; ++p)
                acc += lds_sc[p * C + c] * base[(size_t)lds_pos[p] * H + h];
            atomicAdd(&outp[c * H + h], wl * acc);
        }
    }
}

extern "C" void kernel_launch(void* const* d_in, const int* in_sizes, int n_in,
                              void* d_out, int out_size, void* d_ws, size_t ws_size,
                              hipStream_t stream) {
    const float* hs     = (const float*)d_in[0];
    const int*   ids    = (const int*)d_in[1];
    const float* logits = (const float*)d_in[2];
    const float* W      = (const float*)d_in[3];
    const int*   hte_id = (const int*)d_in[4];
    const int*   dtok   = (const int*)d_in[5];
    const int*   win    = (const int*)d_in[6];

    const int L  = in_sizes[2];                 // 8
    const int CH = in_sizes[3];                 // C*H = 3072
    const int BT = in_sizes[1];                 // B*T
    const int B  = out_size / (2 * CH);         // 16
    const int T  = BT / B;                      // 2048
    const long long total = (long long)in_sizes[0];
    const int H  = (int)(total / ((long long)(L + 1) * BT));  // 768
    const int C  = CH / H;                      // 4
    const int nD = in_sizes[5];                 // 3

    float* out = (float*)d_out;
    mha_zero<<<(out_size + 255) / 256, 256, 0, stream>>>(out, out_size);

    size_t smem = ((size_t)C * H + (size_t)T * C + 2 * C) * sizeof(float)
                + (size_t)T * sizeof(int);
    const int grid = 2 * L * B;
    const int K = (H + 255) / 256;

    if (C == 4 && K == 3 && (H % 4) == 0) {
        mha_fused<4, 3><<<grid, 256, smem, stream>>>(hs, logits, W, ids, hte_id, dtok,
                                                     nD, win, L, B, T, H, out);
    } else if (C == 4 && K == 2 && (H % 4) == 0) {
        mha_fused<4, 2><<<grid, 256, smem, stream>>>(hs, logits, W, ids, hte_id, dtok,
                                                     nD, win, L, B, T, H, out);
    } else if (C == 4 && K == 4 && (H % 4) == 0) {
        mha_fused<4, 4><<<grid, 256, smem, stream>>>(hs, logits, W, ids, hte_id, dtok,
                                                     nD, win, L, B, T, H, out);
    } else if (C == 2 && K == 3 && (H % 4) == 0) {
        mha_fused<2, 3><<<grid, 256, smem, stream>>>(hs, logits, W, ids, hte_id, dtok,
                                                     nD, win, L, B, T, H, out);
    } else if (C == 8 && K == 3 && (H % 4) == 0) {
        mha_fused<8, 3><<<grid, 256, smem, stream>>>(hs, logits, W, ids, hte_id, dtok,
                                                     nD, win, L, B, T, H, out);
    } else {
        mha_fused_gen<<<grid, 256, smem, stream>>>(hs, logits, W, ids, hte_id, dtok,
                                                   nD, win, L, B, T, H, C, out);
    }
}